// Round 10
// baseline (1203.264 us; speedup 1.0000x reference)
//
#include <hip/hip_runtime.h>
#include <stdint.h>

#define T_LEN 8196
#define LOG2E 1.4426950408889634f
#define LN2   0.6931471805599453f
#define INF2  1.4426950e10f   /* 1e10 * log2(e): INF in base-2-scaled units */
#define PD_LD 2080            /* padded E row stride: 16 left + 2048 + 16 right */
#define PD_OFF 16
#define BND_LD 2056           /* boundary row stride: 2048 + 8 dummy slots */

typedef float    f4  __attribute__((ext_vector_type(4)));
typedef unsigned u4  __attribute__((ext_vector_type(4)));
typedef float    vf8 __attribute__((ext_vector_type(8)));

// ---------------------------------------------------------------- helpers
__device__ __forceinline__ float fexp2(float x) {
#if __has_builtin(__builtin_amdgcn_exp2f)
    return __builtin_amdgcn_exp2f(x);
#else
    return __expf(x * LN2);
#endif
}
__device__ __forceinline__ float flog2(float x) {
#if __has_builtin(__builtin_amdgcn_logf)
    return __builtin_amdgcn_logf(x);   // v_log_f32 is base-2
#else
    return __logf(x) * LOG2E;
#endif
}
__device__ __forceinline__ float sigm(float x) { return 1.0f / (1.0f + __expf(-x)); }
__device__ __forceinline__ float tanh_f(float x) {
    x = fminf(fmaxf(x, -15.0f), 15.0f);
    float e = __expf(2.0f * x);
    return (e - 1.0f) / (e + 1.0f);
}

// ------------------------------------------- prep: transpose weights
__global__ void k_prep(const float* __restrict__ Wih1, const float* __restrict__ Whh1,
                       const float* __restrict__ Wih2, const float* __restrict__ Whh2,
                       float* __restrict__ wt) {
    int gid = blockIdx.x * 256 + threadIdx.x;
    if (gid >= 175104) return;
    if (gid < 27648) {
        int k = gid / 384, g = gid % 384;
        wt[gid] = Wih1[g * 72 + k];
    } else if (gid < 76800) {
        int r = gid - 27648; int k = r / 384, g = r % 384;
        wt[gid] = Whh1[g * 128 + k];
    } else if (gid < 125952) {
        int r = gid - 76800; int k = r / 384, g = r % 384;
        wt[gid] = Wih2[g * 128 + k];
    } else {
        int r = gid - 125952; int k = r / 384, g = r % 384;
        wt[gid] = Whh2[g * 128 + k];
    }
}

// ------------------------------------------- GRU features (unchanged)
__global__ __launch_bounds__(256)
void k_gru(const float* __restrict__ X, const float* __restrict__ Y,
           const float* __restrict__ wt,
           const float* __restrict__ bih1, const float* __restrict__ bhh1,
           const float* __restrict__ bih2, const float* __restrict__ bhh2,
           const float* __restrict__ W1, const float* __restrict__ b1,
           float* __restrict__ fbuf) {
    __shared__ __align__(16) float xb[72 * 20];
    __shared__ __align__(16) float h1l[128 * 20];
    __shared__ __align__(16) float h2l[128 * 20];

    const int tid = threadIdx.x;
    const int u = tid & 127;
    const int w0 = (tid >> 7) * 8;
    const int bx = blockIdx.x;
    const int seq = bx >> 7;
    const int wbase = (bx & 127) << 4;
    const float* xp = seq ? Y : X;

    const float* wih1 = wt;
    const float* whh1 = wt + 27648;
    const float* wih2 = wt + 76800;
    const float* whh2 = wt + 125952;

    const float br1  = bih1[u] + bhh1[u];
    const float bz1  = bih1[128 + u] + bhh1[128 + u];
    const float bni1 = bih1[256 + u];
    const float bnh1 = bhh1[256 + u];
    const float br2  = bih2[u] + bhh2[u];
    const float bz2  = bih2[128 + u] + bhh2[128 + u];
    const float bni2 = bih2[256 + u];
    const float bnh2 = bhh2[256 + u];

    float h1r[8], h2r[8];
#pragma unroll
    for (int j = 0; j < 8; ++j) { h1r[j] = 0.f; h2r[j] = 0.f; }
    for (int e = tid; e < 128 * 20; e += 256) { h1l[e] = 0.f; h2l[e] = 0.f; }
    __syncthreads();

    for (int t = 0; t < 8; ++t) {
        for (int e = tid; e < 72 * 16; e += 256) {
            int k = e >> 4, w = e & 15;
            int jj = k / 3, c = k - jj * 3;
            xb[k * 20 + w] = xp[jj * (3 * T_LEN) + c * T_LEN + ((wbase + w) << 2) + t];
        }
        __syncthreads();

        float ar[8], az[8], ai[8], ah[8];
#pragma unroll
        for (int j = 0; j < 8; ++j) { ar[j] = br1; az[j] = bz1; ai[j] = bni1; ah[j] = bnh1; }
        for (int k = 0; k < 72; ++k) {
            float wr = wih1[k * 384 + u];
            float wz = wih1[k * 384 + 128 + u];
            float wn = wih1[k * 384 + 256 + u];
            const float4 x0 = *(const float4*)&xb[k * 20 + w0];
            const float4 x1 = *(const float4*)&xb[k * 20 + w0 + 4];
            float xv[8] = {x0.x, x0.y, x0.z, x0.w, x1.x, x1.y, x1.z, x1.w};
#pragma unroll
            for (int j = 0; j < 8; ++j) {
                ar[j] = fmaf(wr, xv[j], ar[j]);
                az[j] = fmaf(wz, xv[j], az[j]);
                ai[j] = fmaf(wn, xv[j], ai[j]);
            }
        }
        for (int k = 0; k < 128; ++k) {
            float wr = whh1[k * 384 + u];
            float wz = whh1[k * 384 + 128 + u];
            float wn = whh1[k * 384 + 256 + u];
            const float4 x0 = *(const float4*)&h1l[k * 20 + w0];
            const float4 x1 = *(const float4*)&h1l[k * 20 + w0 + 4];
            float xv[8] = {x0.x, x0.y, x0.z, x0.w, x1.x, x1.y, x1.z, x1.w};
#pragma unroll
            for (int j = 0; j < 8; ++j) {
                ar[j] = fmaf(wr, xv[j], ar[j]);
                az[j] = fmaf(wz, xv[j], az[j]);
                ah[j] = fmaf(wn, xv[j], ah[j]);
            }
        }
        __syncthreads();
#pragma unroll
        for (int j = 0; j < 8; ++j) {
            float r = sigm(ar[j]);
            float z = sigm(az[j]);
            float n = tanh_f(ai[j] + r * ah[j]);
            h1r[j] = (1.f - z) * n + z * h1r[j];
        }
#pragma unroll
        for (int j = 0; j < 8; ++j) h1l[u * 20 + w0 + j] = h1r[j];
        __syncthreads();

#pragma unroll
        for (int j = 0; j < 8; ++j) { ar[j] = br2; az[j] = bz2; ai[j] = bni2; ah[j] = bnh2; }
        for (int k = 0; k < 128; ++k) {
            float wr = wih2[k * 384 + u];
            float wz = wih2[k * 384 + 128 + u];
            float wn = wih2[k * 384 + 256 + u];
            const float4 x0 = *(const float4*)&h1l[k * 20 + w0];
            const float4 x1 = *(const float4*)&h1l[k * 20 + w0 + 4];
            float xv[8] = {x0.x, x0.y, x0.z, x0.w, x1.x, x1.y, x1.z, x1.w};
#pragma unroll
            for (int j = 0; j < 8; ++j) {
                ar[j] = fmaf(wr, xv[j], ar[j]);
                az[j] = fmaf(wz, xv[j], az[j]);
                ai[j] = fmaf(wn, xv[j], ai[j]);
            }
        }
        for (int k = 0; k < 128; ++k) {
            float wr = whh2[k * 384 + u];
            float wz = whh2[k * 384 + 128 + u];
            float wn = whh2[k * 384 + 256 + u];
            const float4 x0 = *(const float4*)&h2l[k * 20 + w0];
            const float4 x1 = *(const float4*)&h2l[k * 20 + w0 + 4];
            float xv[8] = {x0.x, x0.y, x0.z, x0.w, x1.x, x1.y, x1.z, x1.w};
#pragma unroll
            for (int j = 0; j < 8; ++j) {
                ar[j] = fmaf(wr, xv[j], ar[j]);
                az[j] = fmaf(wz, xv[j], az[j]);
                ah[j] = fmaf(wn, xv[j], ah[j]);
            }
        }
        __syncthreads();
#pragma unroll
        for (int j = 0; j < 8; ++j) {
            float r = sigm(ar[j]);
            float z = sigm(az[j]);
            float n = tanh_f(ai[j] + r * ah[j]);
            h2r[j] = (1.f - z) * n + z * h2r[j];
        }
#pragma unroll
        for (int j = 0; j < 8; ++j) h2l[u * 20 + w0 + j] = h2r[j];
        __syncthreads();
    }

    for (int idx = tid; idx < 16 * 30; idx += 256) {
        int w = idx / 30, ff = idx - w * 30;
        float acc = b1[ff];
        for (int k = 0; k < 128; ++k) acc = fmaf(h2l[k * 20 + w], W1[ff * 128 + k], acc);
        fbuf[(seq * 2048 + wbase + w) * 32 + ff] = acc;
    }
}

// ------------------------------------------- pairwise sqdist -> E = exp(-D), padded
__global__ __launch_bounds__(256)
void k_pair(const float* __restrict__ fbuf, float* __restrict__ Ep) {
    __shared__ float f1t[64 * 33];
    __shared__ float f2t[64 * 33];
    const int tid = threadIdx.x;
    const int i0 = blockIdx.y * 64, j0 = blockIdx.x * 64;
    for (int e = tid; e < 64 * 32; e += 256) {
        int r = e >> 5, c = e & 31;
        f1t[r * 33 + c] = fbuf[(i0 + r) * 32 + c];
        f2t[r * 33 + c] = fbuf[(2048 + j0 + r) * 32 + c];
    }
    __syncthreads();
    const int tx = tid & 15, ty = tid >> 4;
    float acc[4][4];
#pragma unroll
    for (int r = 0; r < 4; ++r)
#pragma unroll
        for (int c = 0; c < 4; ++c) acc[r][c] = 0.f;
    for (int k = 0; k < 30; ++k) {
        float a[4], b[4];
#pragma unroll
        for (int r = 0; r < 4; ++r) a[r] = f1t[(ty * 4 + r) * 33 + k];
#pragma unroll
        for (int c = 0; c < 4; ++c) b[c] = f2t[(tx * 4 + c) * 33 + k];
#pragma unroll
        for (int r = 0; r < 4; ++r)
#pragma unroll
            for (int c = 0; c < 4; ++c) {
                float d = a[r] - b[c];
                acc[r][c] = fmaf(d, d, acc[r][c]);
            }
    }
#pragma unroll
    for (int r = 0; r < 4; ++r) {
        float4 v = make_float4(__expf(-acc[r][0]), __expf(-acc[r][1]),
                               __expf(-acc[r][2]), __expf(-acc[r][3]));
        *(float4*)&Ep[(size_t)(i0 + ty * 4 + r) * PD_LD + PD_OFF + j0 + tx * 4] = v;
    }
}

// ------------------------------------------- softDTW wavefront, EXP-DOMAIN
// R10: tile + boundary loads as asm volatile (un-sinkable, register-pinned
// "=&v" outputs) + MANUAL vmcnt bookkeeping. Per-macro vmem counts are
// deterministic by construction: 8 tile dwordx4, 4 boundary dwordx4 (b>0,
// all lanes, uniform), 8 publish atomics (b<7, ALWAYS -- out-of-range cols
// go to dummy slots). In-order vmcnt retirement gives exact waits:
//   b=0: 16/macro -> vmcnt(32); b=7: 12/macro -> vmcnt(24); mid: 20 -> vmcnt(40)
// => tile(m) and bnd(m+1) retired, tile(m+1)/(m+2)+bnd in flight. Re-polls
// only ADD outstanding ops => waits get stricter, never unsafe.
#define LOADTILE(P, MM)                                                          \
  {                                                                              \
    int bs = 8 * ((MM) - lane);                                                  \
    bs = bs < -16 ? -16 : (bs > 2048 ? 2048 : bs);                               \
    asm volatile("global_load_dwordx4 %0, %1, off"                               \
                 : "=&v"(P##l0) : "v"(rp0 + bs) : "memory");                     \
    asm volatile("global_load_dwordx4 %0, %1, off"                               \
                 : "=&v"(P##h0) : "v"(rp0 + bs + 4) : "memory");                 \
    asm volatile("global_load_dwordx4 %0, %1, off"                               \
                 : "=&v"(P##l1) : "v"(rp1 + bs) : "memory");                     \
    asm volatile("global_load_dwordx4 %0, %1, off"                               \
                 : "=&v"(P##h1) : "v"(rp1 + bs + 4) : "memory");                 \
    asm volatile("global_load_dwordx4 %0, %1, off"                               \
                 : "=&v"(P##l2) : "v"(rp2 + bs) : "memory");                     \
    asm volatile("global_load_dwordx4 %0, %1, off"                               \
                 : "=&v"(P##h2) : "v"(rp2 + bs + 4) : "memory");                 \
    asm volatile("global_load_dwordx4 %0, %1, off"                               \
                 : "=&v"(P##l3) : "v"(rp3 + bs) : "memory");                     \
    asm volatile("global_load_dwordx4 %0, %1, off"                               \
                 : "=&v"(P##h3) : "v"(rp3 + bs + 4) : "memory");                 \
  }

// boundary: 8 u64 (tag|val) as 4x dwordx4; all lanes, same addresses (bcast)
#define BNDLOAD(S, MM)                                                           \
  if (b > 0) {                                                                   \
    const int p_0 = min(8 * (MM), 2046);                                         \
    const int p_1 = min(8 * (MM) + 2, 2046);                                     \
    const int p_2 = min(8 * (MM) + 4, 2046);                                     \
    const int p_3 = min(8 * (MM) + 6, 2046);                                     \
    asm volatile("global_load_dwordx4 %0, %1, off sc0 sc1"                       \
                 : "=&v"(S##q0) : "v"(bIn + p_0) : "memory");                    \
    asm volatile("global_load_dwordx4 %0, %1, off sc0 sc1"                       \
                 : "=&v"(S##q1) : "v"(bIn + p_1) : "memory");                    \
    asm volatile("global_load_dwordx4 %0, %1, off sc0 sc1"                       \
                 : "=&v"(S##q2) : "v"(bIn + p_2) : "memory");                    \
    asm volatile("global_load_dwordx4 %0, %1, off sc0 sc1"                       \
                 : "=&v"(S##q3) : "v"(bIn + p_3) : "memory");                    \
  }

#define RELOAD1(Q, IDX, P)                                                       \
  { uint64_t t_ = __hip_atomic_load(bIn + (P), __ATOMIC_RELAXED,                 \
                                    __HIP_MEMORY_SCOPE_AGENT);                   \
    Q[(IDX)] = (unsigned)t_; Q[(IDX) + 1] = (unsigned)(t_ >> 32); }

#define VERIFY(S, MM)                                                            \
  {                                                                              \
    const int p_0 = min(8 * (MM), 2046);                                         \
    const int p_1 = min(8 * (MM) + 2, 2046);                                     \
    const int p_2 = min(8 * (MM) + 4, 2046);                                     \
    const int p_3 = min(8 * (MM) + 6, 2046);                                     \
    for (;;) {                                                                   \
        bool bad = (S##q0[1] != (unsigned)p_0) | (S##q0[3] != (unsigned)(p_0+1)) \
                 | (S##q1[1] != (unsigned)p_1) | (S##q1[3] != (unsigned)(p_1+1)) \
                 | (S##q2[1] != (unsigned)p_2) | (S##q2[3] != (unsigned)(p_2+1)) \
                 | (S##q3[1] != (unsigned)p_3) | (S##q3[3] != (unsigned)(p_3+1));\
        if (!__ballot(bad)) break;                                               \
        __builtin_amdgcn_s_sleep(32);                                            \
        RELOAD1(S##q0, 0, p_0) RELOAD1(S##q0, 2, p_0 + 1)                        \
        RELOAD1(S##q1, 0, p_1) RELOAD1(S##q1, 2, p_1 + 1)                        \
        RELOAD1(S##q2, 0, p_2) RELOAD1(S##q2, 2, p_2 + 1)                        \
        RELOAD1(S##q3, 0, p_3) RELOAD1(S##q3, 2, p_3 + 1)                        \
    }                                                                            \
  }

#define DTW_MACRO(CUR, PF, SC_, SI_, M)                                          \
  {                                                                              \
    const int m = (M);                                                           \
    LOADTILE(PF, m + 2)                                                          \
    BNDLOAD(SI_, m + 3)                                                          \
    if (b == 0)      { asm volatile("s_waitcnt vmcnt(32)" ::: "memory"); }       \
    else if (b == 7) { asm volatile("s_waitcnt vmcnt(24)" ::: "memory"); }       \
    else             { asm volatile("s_waitcnt vmcnt(40)" ::: "memory"); }       \
    vf8 Tw;                                                                      \
    _Pragma("unroll")                                                            \
    for (int c = 0; c < 8; ++c) Tw[c] = fexp2(Sc - sIn[c]);                      \
    float Td = fexp2(Sc - carryA);                                               \
    vf8 blog;                                                                    \
    _Pragma("unroll")                                                            \
    for (int c = 0; c < 4; ++c) {                                                \
        float up0 = Tw[c];                                                       \
        float dg0 = (c == 0) ? Td : Tw[(c > 0) ? c - 1 : 0];                     \
        float w0 = CUR##l0[c] * (dg0 + up0 + W0);                                \
        float w1 = CUR##l1[c] * (W0 + w0 + W1);                                  \
        float w2 = CUR##l2[c] * (W1 + w1 + W2);                                  \
        float w3 = CUR##l3[c] * (W2 + w2 + W3);                                  \
        W0 = w0; W1 = w1; W2 = w2; W3 = w3;                                      \
        blog[c] = fminf(Sc - flog2(w3), INF2);                                   \
    }                                                                            \
    _Pragma("unroll")                                                            \
    for (int c = 4; c < 8; ++c) {                                                \
        float up0 = Tw[c];                                                       \
        float dg0 = Tw[c - 1];                                                   \
        float w0 = CUR##h0[c - 4] * (dg0 + up0 + W0);                            \
        float w1 = CUR##h1[c - 4] * (W0 + w0 + W1);                              \
        float w2 = CUR##h2[c - 4] * (W1 + w1 + W2);                              \
        float w3 = CUR##h3[c - 4] * (W2 + w2 + W3);                              \
        W0 = w0; W1 = w1; W2 = w2; W3 = w3;                                      \
        blog[c] = fminf(Sc - flog2(w3), INF2);                                   \
    }                                                                            \
    carryA = sIn[7];                                                             \
    if (lane == 63 && b < 7) {   /* ALWAYS 8 atomics: dummy slot when OOR */     \
        _Pragma("unroll")                                                        \
        for (int c = 0; c < 8; ++c) {                                            \
            int j = 8 * (m - 63) + c;                                            \
            bool inr = (j >= 0) && (j < 2048);                                   \
            uint64_t pk = ((uint64_t)(uint32_t)j << 32) |                        \
                          (uint64_t)__float_as_uint(blog[c]);                    \
            uint64_t* ad = inr ? (bOut + j) : (bOut + 2048 + c);                 \
            (void)__hip_atomic_exchange(ad, pk, __ATOMIC_RELAXED,                \
                                        __HIP_MEMORY_SCOPE_AGENT);               \
        }                                                                        \
    }                                                                            \
    if (lane == 63 && b == 7 && (8 * (m - 63) + 7 == 2047)) res = blog[7];       \
    vf8 sh;                                                                      \
    _Pragma("unroll")                                                            \
    for (int c = 0; c < 8; ++c) sh[c] = __shfl_up(blog[c], 1);                   \
    if (b > 0) VERIFY(SC_, m + 1)                                                \
    if (lane > 0) {                                                              \
        sIn = sh;                                                                \
    } else if (b == 0) {                                                         \
        _Pragma("unroll")                                                        \
        for (int c = 0; c < 8; ++c) sIn[c] = INF2;                               \
    } else {                                                                     \
        sIn[0] = __uint_as_float(SC_##q0[0]); sIn[1] = __uint_as_float(SC_##q0[2]); \
        sIn[2] = __uint_as_float(SC_##q1[0]); sIn[3] = __uint_as_float(SC_##q1[2]); \
        sIn[4] = __uint_as_float(SC_##q2[0]); sIn[5] = __uint_as_float(SC_##q2[2]); \
        sIn[6] = __uint_as_float(SC_##q3[0]); sIn[7] = __uint_as_float(SC_##q3[2]); \
    }                                                                            \
    { /* scale update (uses NEXT macro's incoming mins) */                       \
        float mn = sIn[0];                                                       \
        _Pragma("unroll")                                                        \
        for (int c = 1; c < 8; ++c) mn = fminf(mn, sIn[c]);                      \
        float wmax = fmaxf(fmaxf(W0, W1), fmaxf(W2, W3));                        \
        float Sc_new;                                                            \
        if (wmax > 0.f) {                                                        \
            int e = (int)((__float_as_uint(wmax) >> 23) & 0xFFu) - 127;          \
            Sc_new = fminf(Sc - (float)e, mn + 100.f);                           \
        } else {                                                                 \
            Sc_new = fminf(mn, 1e9f);                                            \
        }                                                                        \
        int dd = (int)fmaxf(fminf(Sc_new - Sc, 999.f), -999.f);                  \
        W0 = ldexpf(W0, dd); W1 = ldexpf(W1, dd);                                \
        W2 = ldexpf(W2, dd); W3 = ldexpf(W3, dd);                                \
        Sc = Sc_new;                                                             \
    }                                                                            \
  }

__global__ __launch_bounds__(64, 1)
void k_dtw(const float* __restrict__ Ep, uint64_t* bndG, float* __restrict__ out) {
    const int b = blockIdx.x;
    const int lane = threadIdx.x;
    const int r0 = b * 256 + lane * 4;
    const uint64_t* bIn = bndG + (size_t)(b - 1) * BND_LD;
    uint64_t* bOut = bndG + (size_t)b * BND_LD;

    const float* rp0 = Ep + (size_t)r0 * PD_LD + PD_OFF;
    const float* rp1 = rp0 + PD_LD;
    const float* rp2 = rp1 + PD_LD;
    const float* rp3 = rp2 + PD_LD;

    float W0 = 0.f, W1 = 0.f, W2 = 0.f, W3 = 0.f;
    float Sc = 0.f;
    float carryA = (b == 0 && lane == 0) ? 0.f : INF2;  // seed: A(-1,-1)=0
    float res = 0.f;
    vf8 sIn;
#pragma unroll
    for (int c = 0; c < 8; ++c) sIn[c] = INF2;

    // tile ring (3 bufs x 4 rows x lo/hi) and boundary ring (3 slots x 4 q)
    f4 Al0, Ah0, Al1, Ah1, Al2, Ah2, Al3, Ah3;
    f4 Bl0, Bh0, Bl1, Bh1, Bl2, Bh2, Bl3, Bh3;
    f4 Cl0, Ch0, Cl1, Ch1, Cl2, Ch2, Cl3, Ch3;
    u4 S0q0, S0q1, S0q2, S0q3;
    u4 S1q0, S1q1, S1q2, S1q3;
    u4 S2q0, S2q1, S2q2, S2q3;

    if (b > 0 && lane == 0) {
        // startup SLACK: wait until producer is ~64 cols past our need
        uint64_t p = __hip_atomic_load(&bIn[71], __ATOMIC_RELAXED,
                                       __HIP_MEMORY_SCOPE_AGENT);
        while ((uint32_t)(p >> 32) != 71u) {
            __builtin_amdgcn_s_sleep(8);
            p = __hip_atomic_load(&bIn[71], __ATOMIC_RELAXED,
                                  __HIP_MEMORY_SCOPE_AGENT);
        }
    }
    if (b > 0) {
        // blocking poll for macro-0 boundary (cols 0..7) + scale seed (all lanes)
        uint64_t pv[8];
        for (;;) {
            bool again = false;
#pragma unroll
            for (int u = 0; u < 8; ++u) {
                pv[u] = __hip_atomic_load(&bIn[u], __ATOMIC_RELAXED,
                                          __HIP_MEMORY_SCOPE_AGENT);
                if ((uint32_t)(pv[u] >> 32) != (uint32_t)u) again = true;
            }
            if (!again) break;
            __builtin_amdgcn_s_sleep(2);
        }
        if (lane == 0) {
            float mn = INF2;
#pragma unroll
            for (int u = 0; u < 8; ++u) {
                sIn[u] = __uint_as_float((uint32_t)pv[u]);
                mn = fminf(mn, sIn[u]);
            }
            Sc = fminf(mn, 1e9f);
        }
    }

    // prime rings: tiles for macros 0,1; boundary slots for macros 1,2
    LOADTILE(A, 0)
    LOADTILE(B, 1)
    BNDLOAD(S1, 1)
    BNDLOAD(S2, 2)
    asm volatile("s_waitcnt vmcnt(0)" ::: "memory");   // reset count state

    // 321 macro-steps of 8 cols (lane63 hits col 2047 at m=318); 321 = 3*107
    for (int mm = 0; mm < 321; mm += 3) {
        DTW_MACRO(A, C, S1, S0, mm)
        DTW_MACRO(B, A, S2, S1, mm + 1)
        DTW_MACRO(C, B, S0, S2, mm + 2)
    }

    if (b == 7 && lane == 63) out[0] = res * LN2;   // back to base-e units
}

// ------------------------------------------- launch
extern "C" void kernel_launch(void* const* d_in, const int* in_sizes, int n_in,
                              void* d_out, int out_size, void* d_ws, size_t ws_size,
                              hipStream_t stream) {
    const float* X    = (const float*)d_in[0];
    const float* Y    = (const float*)d_in[1];
    const float* Wih1 = (const float*)d_in[2];
    const float* Whh1 = (const float*)d_in[3];
    const float* bih1 = (const float*)d_in[4];
    const float* bhh1 = (const float*)d_in[5];
    const float* Wih2 = (const float*)d_in[6];
    const float* Whh2 = (const float*)d_in[7];
    const float* bih2 = (const float*)d_in[8];
    const float* bhh2 = (const float*)d_in[9];
    const float* W1   = (const float*)d_in[10];
    const float* b1   = (const float*)d_in[11];
    float* out = (float*)d_out;

    // Layout (floats). wt overlaps Ep's tail (dead after k_gru; k_pair
    // overwrites all of Ep afterwards). ~17.7 MB total.
    float* ws   = (float*)d_ws;
    float* fbuf = ws;                            // 131072 floats
    uint64_t* bndG = (uint64_t*)(ws + 131072);   // 7*2056 u64 = 28784 fl -> 28800
    float* Ep   = ws + 131072 + 28800;           // 2048*2080 = 4259840 floats
    float* wt   = Ep + 4259840 - 175104;         // overlapped tail

    k_prep<<<684, 256, 0, stream>>>(Wih1, Whh1, Wih2, Whh2, wt);
    k_gru<<<256, 256, 0, stream>>>(X, Y, wt, bih1, bhh1, bih2, bhh2, W1, b1, fbuf);
    k_pair<<<dim3(32, 32), 256, 0, stream>>>(fbuf, Ep);
    k_dtw<<<8, 64, 0, stream>>>(Ep, bndG, out);
}

// Round 12
// 1174.564 us; speedup vs baseline: 1.0244x; 1.0244x over previous
//
#include <hip/hip_runtime.h>
#include <stdint.h>

#define T_LEN 8196
#define LOG2E 1.4426950408889634f
#define LN2   0.6931471805599453f
#define INF2  1.4426950e10f   /* 1e10 * log2(e): INF in base-2-scaled units */
#define PD_LD 2080            /* padded E row stride: 16 left + 2048 + 16 right */
#define PD_OFF 16
#define BND_LD 2056           /* boundary row stride: 2048 + 8 dummy slots */

typedef float    f4  __attribute__((ext_vector_type(4)));
typedef unsigned u4  __attribute__((ext_vector_type(4)));

// ---------------------------------------------------------------- helpers
__device__ __forceinline__ float fexp2(float x) {
#if __has_builtin(__builtin_amdgcn_exp2f)
    return __builtin_amdgcn_exp2f(x);
#else
    return __expf(x * LN2);
#endif
}
__device__ __forceinline__ float flog2(float x) {
#if __has_builtin(__builtin_amdgcn_logf)
    return __builtin_amdgcn_logf(x);   // v_log_f32 is base-2
#else
    return __logf(x) * LOG2E;
#endif
}
__device__ __forceinline__ float sigm(float x) { return 1.0f / (1.0f + __expf(-x)); }
__device__ __forceinline__ float tanh_f(float x) {
    x = fminf(fmaxf(x, -15.0f), 15.0f);
    float e = __expf(2.0f * x);
    return (e - 1.0f) / (e + 1.0f);
}

// ------------------------------------------- prep: transpose weights
__global__ void k_prep(const float* __restrict__ Wih1, const float* __restrict__ Whh1,
                       const float* __restrict__ Wih2, const float* __restrict__ Whh2,
                       float* __restrict__ wt) {
    int gid = blockIdx.x * 256 + threadIdx.x;
    if (gid >= 175104) return;
    if (gid < 27648) {
        int k = gid / 384, g = gid % 384;
        wt[gid] = Wih1[g * 72 + k];
    } else if (gid < 76800) {
        int r = gid - 27648; int k = r / 384, g = r % 384;
        wt[gid] = Whh1[g * 128 + k];
    } else if (gid < 125952) {
        int r = gid - 76800; int k = r / 384, g = r % 384;
        wt[gid] = Wih2[g * 128 + k];
    } else {
        int r = gid - 125952; int k = r / 384, g = r % 384;
        wt[gid] = Whh2[g * 128 + k];
    }
}

// ------------------------------------------- GRU features (unchanged)
__global__ __launch_bounds__(256)
void k_gru(const float* __restrict__ X, const float* __restrict__ Y,
           const float* __restrict__ wt,
           const float* __restrict__ bih1, const float* __restrict__ bhh1,
           const float* __restrict__ bih2, const float* __restrict__ bhh2,
           const float* __restrict__ W1, const float* __restrict__ b1,
           float* __restrict__ fbuf) {
    __shared__ __align__(16) float xb[72 * 20];
    __shared__ __align__(16) float h1l[128 * 20];
    __shared__ __align__(16) float h2l[128 * 20];

    const int tid = threadIdx.x;
    const int u = tid & 127;
    const int w0 = (tid >> 7) * 8;
    const int bx = blockIdx.x;
    const int seq = bx >> 7;
    const int wbase = (bx & 127) << 4;
    const float* xp = seq ? Y : X;

    const float* wih1 = wt;
    const float* whh1 = wt + 27648;
    const float* wih2 = wt + 76800;
    const float* whh2 = wt + 125952;

    const float br1  = bih1[u] + bhh1[u];
    const float bz1  = bih1[128 + u] + bhh1[128 + u];
    const float bni1 = bih1[256 + u];
    const float bnh1 = bhh1[256 + u];
    const float br2  = bih2[u] + bhh2[u];
    const float bz2  = bih2[128 + u] + bhh2[128 + u];
    const float bni2 = bih2[256 + u];
    const float bnh2 = bhh2[256 + u];

    float h1r[8], h2r[8];
#pragma unroll
    for (int j = 0; j < 8; ++j) { h1r[j] = 0.f; h2r[j] = 0.f; }
    for (int e = tid; e < 128 * 20; e += 256) { h1l[e] = 0.f; h2l[e] = 0.f; }
    __syncthreads();

    for (int t = 0; t < 8; ++t) {
        for (int e = tid; e < 72 * 16; e += 256) {
            int k = e >> 4, w = e & 15;
            int jj = k / 3, c = k - jj * 3;
            xb[k * 20 + w] = xp[jj * (3 * T_LEN) + c * T_LEN + ((wbase + w) << 2) + t];
        }
        __syncthreads();

        float ar[8], az[8], ai[8], ah[8];
#pragma unroll
        for (int j = 0; j < 8; ++j) { ar[j] = br1; az[j] = bz1; ai[j] = bni1; ah[j] = bnh1; }
        for (int k = 0; k < 72; ++k) {
            float wr = wih1[k * 384 + u];
            float wz = wih1[k * 384 + 128 + u];
            float wn = wih1[k * 384 + 256 + u];
            const float4 x0 = *(const float4*)&xb[k * 20 + w0];
            const float4 x1 = *(const float4*)&xb[k * 20 + w0 + 4];
            float xv[8] = {x0.x, x0.y, x0.z, x0.w, x1.x, x1.y, x1.z, x1.w};
#pragma unroll
            for (int j = 0; j < 8; ++j) {
                ar[j] = fmaf(wr, xv[j], ar[j]);
                az[j] = fmaf(wz, xv[j], az[j]);
                ai[j] = fmaf(wn, xv[j], ai[j]);
            }
        }
        for (int k = 0; k < 128; ++k) {
            float wr = whh1[k * 384 + u];
            float wz = whh1[k * 384 + 128 + u];
            float wn = whh1[k * 384 + 256 + u];
            const float4 x0 = *(const float4*)&h1l[k * 20 + w0];
            const float4 x1 = *(const float4*)&h1l[k * 20 + w0 + 4];
            float xv[8] = {x0.x, x0.y, x0.z, x0.w, x1.x, x1.y, x1.z, x1.w};
#pragma unroll
            for (int j = 0; j < 8; ++j) {
                ar[j] = fmaf(wr, xv[j], ar[j]);
                az[j] = fmaf(wz, xv[j], az[j]);
                ah[j] = fmaf(wn, xv[j], ah[j]);
            }
        }
        __syncthreads();
#pragma unroll
        for (int j = 0; j < 8; ++j) {
            float r = sigm(ar[j]);
            float z = sigm(az[j]);
            float n = tanh_f(ai[j] + r * ah[j]);
            h1r[j] = (1.f - z) * n + z * h1r[j];
        }
#pragma unroll
        for (int j = 0; j < 8; ++j) h1l[u * 20 + w0 + j] = h1r[j];
        __syncthreads();

#pragma unroll
        for (int j = 0; j < 8; ++j) { ar[j] = br2; az[j] = bz2; ai[j] = bni2; ah[j] = bnh2; }
        for (int k = 0; k < 128; ++k) {
            float wr = wih2[k * 384 + u];
            float wz = wih2[k * 384 + 128 + u];
            float wn = wih2[k * 384 + 256 + u];
            const float4 x0 = *(const float4*)&h1l[k * 20 + w0];
            const float4 x1 = *(const float4*)&h1l[k * 20 + w0 + 4];
            float xv[8] = {x0.x, x0.y, x0.z, x0.w, x1.x, x1.y, x1.z, x1.w};
#pragma unroll
            for (int j = 0; j < 8; ++j) {
                ar[j] = fmaf(wr, xv[j], ar[j]);
                az[j] = fmaf(wz, xv[j], az[j]);
                ai[j] = fmaf(wn, xv[j], ai[j]);
            }
        }
        for (int k = 0; k < 128; ++k) {
            float wr = whh2[k * 384 + u];
            float wz = whh2[k * 384 + 128 + u];
            float wn = whh2[k * 384 + 256 + u];
            const float4 x0 = *(const float4*)&h2l[k * 20 + w0];
            const float4 x1 = *(const float4*)&h2l[k * 20 + w0 + 4];
            float xv[8] = {x0.x, x0.y, x0.z, x0.w, x1.x, x1.y, x1.z, x1.w};
#pragma unroll
            for (int j = 0; j < 8; ++j) {
                ar[j] = fmaf(wr, xv[j], ar[j]);
                az[j] = fmaf(wz, xv[j], az[j]);
                ah[j] = fmaf(wn, xv[j], ah[j]);
            }
        }
        __syncthreads();
#pragma unroll
        for (int j = 0; j < 8; ++j) {
            float r = sigm(ar[j]);
            float z = sigm(az[j]);
            float n = tanh_f(ai[j] + r * ah[j]);
            h2r[j] = (1.f - z) * n + z * h2r[j];
        }
#pragma unroll
        for (int j = 0; j < 8; ++j) h2l[u * 20 + w0 + j] = h2r[j];
        __syncthreads();
    }

    for (int idx = tid; idx < 16 * 30; idx += 256) {
        int w = idx / 30, ff = idx - w * 30;
        float acc = b1[ff];
        for (int k = 0; k < 128; ++k) acc = fmaf(h2l[k * 20 + w], W1[ff * 128 + k], acc);
        fbuf[(seq * 2048 + wbase + w) * 32 + ff] = acc;
    }
}

// ------------------------------------------- pairwise sqdist -> E = exp(-D), padded
__global__ __launch_bounds__(256)
void k_pair(const float* __restrict__ fbuf, float* __restrict__ Ep) {
    __shared__ float f1t[64 * 33];
    __shared__ float f2t[64 * 33];
    const int tid = threadIdx.x;
    const int i0 = blockIdx.y * 64, j0 = blockIdx.x * 64;
    for (int e = tid; e < 64 * 32; e += 256) {
        int r = e >> 5, c = e & 31;
        f1t[r * 33 + c] = fbuf[(i0 + r) * 32 + c];
        f2t[r * 33 + c] = fbuf[(2048 + j0 + r) * 32 + c];
    }
    __syncthreads();
    const int tx = tid & 15, ty = tid >> 4;
    float acc[4][4];
#pragma unroll
    for (int r = 0; r < 4; ++r)
#pragma unroll
        for (int c = 0; c < 4; ++c) acc[r][c] = 0.f;
    for (int k = 0; k < 30; ++k) {
        float a[4], b[4];
#pragma unroll
        for (int r = 0; r < 4; ++r) a[r] = f1t[(ty * 4 + r) * 33 + k];
#pragma unroll
        for (int c = 0; c < 4; ++c) b[c] = f2t[(tx * 4 + c) * 33 + k];
#pragma unroll
        for (int r = 0; r < 4; ++r)
#pragma unroll
            for (int c = 0; c < 4; ++c) {
                float d = a[r] - b[c];
                acc[r][c] = fmaf(d, d, acc[r][c]);
            }
    }
#pragma unroll
    for (int r = 0; r < 4; ++r) {
        float4 v = make_float4(__expf(-acc[r][0]), __expf(-acc[r][1]),
                               __expf(-acc[r][2]), __expf(-acc[r][3]));
        *(float4*)&Ep[(size_t)(i0 + ty * 4 + r) * PD_LD + PD_OFF + j0 + tx * 4] = v;
    }
}

// ------------------------------------------- softDTW wavefront, EXP-DOMAIN
// R12 = R10's PROVEN-CORRECT asm-load + manual-vmcnt protocol, downsized to
// 4-col macros so the live set (~105 regs: 3-deep tile ring 48 + 3-deep bnd
// ring 24 + working ~33) FITS the allocator's budget -- R10's 8-col version
// demanded ~190 live and the allocator spilled the asm results to scratch
// (WRITE_SIZE +114KB, dur 655->820). Deterministic vmem ops/macro: 4 tile
// loads, 2 bnd loads (b>0), 4 publishes (b<7, dummy-padded). In-order vmcnt
// retirement -> single wait guarantees tile(m) AND bnd(m+1) retired:
//   mid vmcnt(20), b=0 vmcnt(16), b=7 vmcnt(12); tiles m+1,m+2 in flight.
#define LOADTILE(P, MM)                                                          \
  {                                                                              \
    int bs = 4 * ((MM) - lane);                                                  \
    bs = bs < -16 ? -16 : (bs > 2048 ? 2048 : bs);                               \
    asm volatile("global_load_dwordx4 %0, %1, off"                               \
                 : "=&v"(P##r0) : "v"(rp0 + bs) : "memory");                     \
    asm volatile("global_load_dwordx4 %0, %1, off"                               \
                 : "=&v"(P##r1) : "v"(rp1 + bs) : "memory");                     \
    asm volatile("global_load_dwordx4 %0, %1, off"                               \
                 : "=&v"(P##r2) : "v"(rp2 + bs) : "memory");                     \
    asm volatile("global_load_dwordx4 %0, %1, off"                               \
                 : "=&v"(P##r3) : "v"(rp3 + bs) : "memory");                     \
  }

// boundary: 4 u64 (tag|val) as 2x dwordx4; all lanes, same addresses (bcast)
#define BNDLOAD(S, MM)                                                           \
  if (b > 0) {                                                                   \
    int p = 4 * (MM); p = p > 2044 ? 2044 : p;                                   \
    asm volatile("global_load_dwordx4 %0, %1, off sc0 sc1"                       \
                 : "=&v"(S##q0) : "v"(bIn + p) : "memory");                      \
    asm volatile("global_load_dwordx4 %0, %1, off sc0 sc1"                       \
                 : "=&v"(S##q1) : "v"(bIn + p + 2) : "memory");                  \
  }

#define VERIFY(S, MM)                                                            \
  {                                                                              \
    int p = 4 * (MM); p = p > 2044 ? 2044 : p;                                   \
    for (;;) {                                                                   \
        bool bad = (S##q0[1] != (unsigned)p)     | (S##q0[3] != (unsigned)(p+1)) \
                 | (S##q1[1] != (unsigned)(p+2)) | (S##q1[3] != (unsigned)(p+3));\
        if (!__ballot(bad)) break;                                               \
        __builtin_amdgcn_s_sleep(32);                                            \
        uint64_t t_;                                                             \
        t_ = __hip_atomic_load(bIn + p,     __ATOMIC_RELAXED, __HIP_MEMORY_SCOPE_AGENT); S##q0[0]=(unsigned)t_; S##q0[1]=(unsigned)(t_>>32); \
        t_ = __hip_atomic_load(bIn + p + 1, __ATOMIC_RELAXED, __HIP_MEMORY_SCOPE_AGENT); S##q0[2]=(unsigned)t_; S##q0[3]=(unsigned)(t_>>32); \
        t_ = __hip_atomic_load(bIn + p + 2, __ATOMIC_RELAXED, __HIP_MEMORY_SCOPE_AGENT); S##q1[0]=(unsigned)t_; S##q1[1]=(unsigned)(t_>>32); \
        t_ = __hip_atomic_load(bIn + p + 3, __ATOMIC_RELAXED, __HIP_MEMORY_SCOPE_AGENT); S##q1[2]=(unsigned)t_; S##q1[3]=(unsigned)(t_>>32); \
    }                                                                            \
  }

#define DTW_MACRO(CUR, PF, SC_, SI_, M)                                          \
  {                                                                              \
    const int m = (M);                                                           \
    LOADTILE(PF, m + 2)                                                          \
    BNDLOAD(SI_, m + 3)                                                          \
    if (b == 0)      { asm volatile("s_waitcnt vmcnt(16)" ::: "memory"); }       \
    else if (b == 7) { asm volatile("s_waitcnt vmcnt(12)" ::: "memory"); }       \
    else             { asm volatile("s_waitcnt vmcnt(20)" ::: "memory"); }       \
    f4 Tw;                                                                       \
    _Pragma("unroll")                                                            \
    for (int c = 0; c < 4; ++c) Tw[c] = fexp2(Sc - sIn[c]);                      \
    float Td = fexp2(Sc - carryA);                                               \
    f4 blog;                                                                     \
    _Pragma("unroll")                                                            \
    for (int c = 0; c < 4; ++c) {                                                \
        float up0 = Tw[c];                                                       \
        float dg0 = (c == 0) ? Td : Tw[(c > 0) ? c - 1 : 0];                     \
        float w0 = CUR##r0[c] * (dg0 + up0 + W0);                                \
        float w1 = CUR##r1[c] * (W0 + w0 + W1);                                  \
        float w2 = CUR##r2[c] * (W1 + w1 + W2);                                  \
        float w3 = CUR##r3[c] * (W2 + w2 + W3);                                  \
        W0 = w0; W1 = w1; W2 = w2; W3 = w3;                                      \
        blog[c] = fminf(Sc - flog2(w3), INF2);                                   \
    }                                                                            \
    carryA = sIn[3];                                                             \
    if (lane == 63 && b < 7) {   /* ALWAYS 4 atomics: dummy slot when OOR */     \
        _Pragma("unroll")                                                        \
        for (int c = 0; c < 4; ++c) {                                            \
            int j = 4 * (m - 63) + c;                                            \
            bool inr = (j >= 0) && (j < 2048);                                   \
            uint64_t pk = ((uint64_t)(uint32_t)j << 32) |                        \
                          (uint64_t)__float_as_uint(blog[c]);                    \
            uint64_t* ad = inr ? (bOut + j) : (bOut + 2048 + c);                 \
            (void)__hip_atomic_exchange(ad, pk, __ATOMIC_RELAXED,                \
                                        __HIP_MEMORY_SCOPE_AGENT);               \
        }                                                                        \
    }                                                                            \
    if (lane == 63 && b == 7 && (4 * (m - 63) + 3 == 2047)) res = blog[3];       \
    f4 sh;                                                                       \
    _Pragma("unroll")                                                            \
    for (int c = 0; c < 4; ++c) sh[c] = __shfl_up(blog[c], 1);                   \
    f4 bv;                                                                       \
    _Pragma("unroll")                                                            \
    for (int c = 0; c < 4; ++c) bv[c] = INF2;                                    \
    if (b > 0 && m <= 510) {                                                     \
        VERIFY(SC_, m + 1)                                                       \
        bv[0] = __uint_as_float(SC_##q0[0]); bv[1] = __uint_as_float(SC_##q0[2]);\
        bv[2] = __uint_as_float(SC_##q1[0]); bv[3] = __uint_as_float(SC_##q1[2]);\
    }                                                                            \
    if (lane > 0) {                                                              \
        sIn = sh;                                                                \
    } else if (b == 0) {                                                         \
        _Pragma("unroll")                                                        \
        for (int c = 0; c < 4; ++c) sIn[c] = INF2;                               \
    } else {                                                                     \
        sIn = bv;                                                                \
    }                                                                            \
    { /* scale update (uses NEXT macro's incoming mins) */                       \
        float mn = fminf(fminf(sIn[0], sIn[1]), fminf(sIn[2], sIn[3]));          \
        float wmax = fmaxf(fmaxf(W0, W1), fmaxf(W2, W3));                        \
        float Sc_new;                                                            \
        if (wmax > 0.f) {                                                        \
            int e = (int)((__float_as_uint(wmax) >> 23) & 0xFFu) - 127;          \
            Sc_new = fminf(Sc - (float)e, mn + 100.f);                           \
        } else {                                                                 \
            Sc_new = fminf(mn, 1e9f);                                            \
        }                                                                        \
        int dd = (int)fmaxf(fminf(Sc_new - Sc, 999.f), -999.f);                  \
        W0 = ldexpf(W0, dd); W1 = ldexpf(W1, dd);                                \
        W2 = ldexpf(W2, dd); W3 = ldexpf(W3, dd);                                \
        Sc = Sc_new;                                                             \
    }                                                                            \
  }

__global__ __launch_bounds__(64, 1)
void k_dtw(const float* __restrict__ Ep, uint64_t* bndG, float* __restrict__ out) {
    const int b = blockIdx.x;
    const int lane = threadIdx.x;
    const int r0 = b * 256 + lane * 4;
    const uint64_t* bIn = bndG + (size_t)(b - 1) * BND_LD;
    uint64_t* bOut = bndG + (size_t)b * BND_LD;

    const float* rp0 = Ep + (size_t)r0 * PD_LD + PD_OFF;
    const float* rp1 = rp0 + PD_LD;
    const float* rp2 = rp1 + PD_LD;
    const float* rp3 = rp2 + PD_LD;

    float W0 = 0.f, W1 = 0.f, W2 = 0.f, W3 = 0.f;
    float Sc = 0.f;
    float carryA = (b == 0 && lane == 0) ? 0.f : INF2;  // seed: A(-1,-1)=0
    float res = 0.f;
    f4 sIn;
#pragma unroll
    for (int c = 0; c < 4; ++c) sIn[c] = INF2;

    // tile ring (3 bufs x 4 rows) and boundary ring (3 slots x 2 quads)
    f4 Ar0, Ar1, Ar2, Ar3;
    f4 Br0, Br1, Br2, Br3;
    f4 Cr0, Cr1, Cr2, Cr3;
    u4 S0q0, S0q1, S1q0, S1q1, S2q0, S2q1;

    if (b > 0 && lane == 0) {
        // startup SLACK: wait until producer is ~64 cols past our need
        uint64_t p = __hip_atomic_load(&bIn[71], __ATOMIC_RELAXED,
                                       __HIP_MEMORY_SCOPE_AGENT);
        while ((uint32_t)(p >> 32) != 71u) {
            __builtin_amdgcn_s_sleep(8);
            p = __hip_atomic_load(&bIn[71], __ATOMIC_RELAXED,
                                  __HIP_MEMORY_SCOPE_AGENT);
        }
    }
    if (b > 0) {
        // blocking poll for macro-0 boundary (cols 0..3) + scale seed
        uint64_t pv[4];
        for (;;) {
            bool again = false;
#pragma unroll
            for (int u = 0; u < 4; ++u) {
                pv[u] = __hip_atomic_load(&bIn[u], __ATOMIC_RELAXED,
                                          __HIP_MEMORY_SCOPE_AGENT);
                if ((uint32_t)(pv[u] >> 32) != (uint32_t)u) again = true;
            }
            if (!again) break;
            __builtin_amdgcn_s_sleep(2);
        }
        if (lane == 0) {
            float mn = INF2;
#pragma unroll
            for (int u = 0; u < 4; ++u) {
                sIn[u] = __uint_as_float((uint32_t)pv[u]);
                mn = fminf(mn, sIn[u]);
            }
            Sc = fminf(mn, 1e9f);
        }
    }

    // prime rings: tiles for macros 0,1; bnd slots for macros 1 (cols 4..7)
    // and 2 (cols 8..11)
    LOADTILE(A, 0)
    LOADTILE(B, 1)
    BNDLOAD(S1, 1)
    BNDLOAD(S2, 2)
    asm volatile("s_waitcnt vmcnt(0)" ::: "memory");   // drain; reset count state

    // 576 macro-steps of 4 cols (lane63 hits col 2047 at m=574); 576 = 3*192
    for (int mm = 0; mm < 576; mm += 3) {
        DTW_MACRO(A, C, S1, S0, mm)
        DTW_MACRO(B, A, S2, S1, mm + 1)
        DTW_MACRO(C, B, S0, S2, mm + 2)
    }

    if (b == 7 && lane == 63) out[0] = res * LN2;   // back to base-e units
}

// ------------------------------------------- launch
extern "C" void kernel_launch(void* const* d_in, const int* in_sizes, int n_in,
                              void* d_out, int out_size, void* d_ws, size_t ws_size,
                              hipStream_t stream) {
    const float* X    = (const float*)d_in[0];
    const float* Y    = (const float*)d_in[1];
    const float* Wih1 = (const float*)d_in[2];
    const float* Whh1 = (const float*)d_in[3];
    const float* bih1 = (const float*)d_in[4];
    const float* bhh1 = (const float*)d_in[5];
    const float* Wih2 = (const float*)d_in[6];
    const float* Whh2 = (const float*)d_in[7];
    const float* bih2 = (const float*)d_in[8];
    const float* bhh2 = (const float*)d_in[9];
    const float* W1   = (const float*)d_in[10];
    const float* b1   = (const float*)d_in[11];
    float* out = (float*)d_out;

    // Layout (floats). wt overlaps Ep's tail (dead after k_gru; k_pair
    // overwrites all of Ep afterwards). ~17.7 MB total.
    float* ws   = (float*)d_ws;
    float* fbuf = ws;                            // 131072 floats
    uint64_t* bndG = (uint64_t*)(ws + 131072);   // 7*2056 u64 = 28784 fl -> 28800
    float* Ep   = ws + 131072 + 28800;           // 2048*2080 = 4259840 floats
    float* wt   = Ep + 4259840 - 175104;         // overlapped tail

    k_prep<<<684, 256, 0, stream>>>(Wih1, Whh1, Wih2, Whh2, wt);
    k_gru<<<256, 256, 0, stream>>>(X, Y, wt, bih1, bhh1, bih2, bhh2, W1, b1, fbuf);
    k_pair<<<dim3(32, 32), 256, 0, stream>>>(fbuf, Ep);
    k_dtw<<<8, 64, 0, stream>>>(Ep, bndG, out);
}